// Round 7
// baseline (553.146 us; speedup 1.0000x reference)
//
#include <hip/hip_runtime.h>
#include <math.h>

#define PN 2048
#define PC 1024
#define PH 8
#define PD 128
#define PC3 3072

typedef __bf16 bf16x8 __attribute__((ext_vector_type(8)));
typedef float  f32x4  __attribute__((ext_vector_type(4)));
typedef short  s8v    __attribute__((ext_vector_type(8)));
typedef short  s4v    __attribute__((ext_vector_type(4)));

__device__ __forceinline__ short f2bf(float x) {
    unsigned u = __float_as_uint(x);
    unsigned r = (u + 0x7fffu + ((u >> 16) & 1u)) >> 16;
    return (short)r;
}
__device__ __forceinline__ float bf2f(short s) {
    return __uint_as_float(((unsigned)(unsigned short)s) << 16);
}

#define LDS_DMA(g, l) __builtin_amdgcn_global_load_lds( \
    (const __attribute__((address_space(1))) void*)(g), \
    (__attribute__((address_space(3))) void*)(l), 16, 0, 0)

// ---------------- bf16 MFMA GEMM:  C = alpha * A @ B^T (+bias) ----------------
template<int BN, bool OBF16, bool BIAS>
__global__ __launch_bounds__(256) void mfma_gemm_k(
    const short* __restrict__ A, int lda, long zsa,
    const short* __restrict__ B, int ldb, long zsb,
    void* __restrict__ Cv, int ldc, long zsc,
    int K, float alpha, const float* __restrict__ bias)
{
    constexpr int NJ = BN / 32;
    __shared__ short As[128 * 32];
    __shared__ short Bs[BN * 32];
    const int tid = threadIdx.x;
    const int wave = tid >> 6, lane = tid & 63;
    const int lrow = tid >> 2;
    const int lcol = (tid & 3) * 8;
    const int z = blockIdx.z;
    A += (long)z * zsa;
    B += (long)z * zsb;
    const int row0 = blockIdx.y * 128, col0 = blockIdx.x * BN;
    const short* Ag = A + (long)(row0 + lrow) * lda + lcol;
    const short* Bg = B + (long)(col0 + lrow) * ldb + lcol;
    short* AsW0 = As + wave * 512;
    short* AsW1 = As + 2048 + wave * 512;
    short* BsW0 = Bs + wave * 512;
    short* BsW1 = Bs + 2048 + wave * 512;
    const int wr = (wave >> 1) * 64, wc = (wave & 1) * (BN / 2);
    const int m16 = lane & 15, q8 = (lane >> 4) * 8;

    f32x4 acc[4][NJ];
#pragma unroll
    for (int i = 0; i < 4; ++i)
#pragma unroll
        for (int j = 0; j < NJ; ++j) acc[i][j] = (f32x4){0.f, 0.f, 0.f, 0.f};

    for (int kt = 0; kt < K; kt += 32) {
        if (kt) __syncthreads();
        LDS_DMA(Ag + kt, AsW0);
        LDS_DMA(Ag + kt + 64 * (long)lda, AsW1);
        LDS_DMA(Bg + kt, BsW0);
        if (BN == 128) LDS_DMA(Bg + kt + 64 * (long)ldb, BsW1);
        __syncthreads();
        bf16x8 a[4], b[NJ];
#pragma unroll
        for (int i = 0; i < 4; ++i)
            a[i] = *(const bf16x8*)&As[(wr + i * 16 + m16) * 32 + q8];
#pragma unroll
        for (int j = 0; j < NJ; ++j)
            b[j] = *(const bf16x8*)&Bs[(wc + j * 16 + m16) * 32 + q8];
#pragma unroll
        for (int i = 0; i < 4; ++i)
#pragma unroll
            for (int j = 0; j < NJ; ++j)
                acc[i][j] = __builtin_amdgcn_mfma_f32_16x16x32_bf16(a[i], b[j], acc[i][j], 0, 0, 0);
    }

    const long cz = (long)z * zsc;
#pragma unroll
    for (int i = 0; i < 4; ++i) {
        const int r0 = row0 + wr + i * 16 + (lane >> 4) * 4;
#pragma unroll
        for (int j = 0; j < NJ; ++j) {
            const int c = col0 + wc + j * 16 + m16;
            const float bv = BIAS ? bias[c] : 0.0f;
#pragma unroll
            for (int t = 0; t < 4; ++t) {
                const float x = acc[i][j][t] * alpha + bv;
                const long off = cz + (long)(r0 + t) * ldc + c;
                if (OBF16) ((short*)Cv)[off] = f2bf(x);
                else       ((float*)Cv)[off] = x;
            }
        }
    }
}

// ---------------- attention kernel A: softmax row sums (NO LDS staging) ----------------
// grid (16 row-tiles, 8 heads, 8 = side*4 + colchunk); atomicAdd partial sums.
// Fragments loaded directly from global (16B/lane, 16 rows x 64B per instr).
__global__ __launch_bounds__(256) void attn_rowsum_k(
    const short* __restrict__ qkv,
    const float* __restrict__ cls_score, const float* __restrict__ fg_score,
    float* __restrict__ l_g)
{
    __shared__ float lsum[128][2];
    const int tid = threadIdx.x, wave = tid >> 6, lane = tid & 63;
    const int wr = (wave >> 1) * 64, wc = (wave & 1) * 64;
    const int m16 = lane & 15, q4 = lane >> 4, q8 = q4 * 8;
    const int row0 = blockIdx.x * 128, h = blockIdx.y;
    const int side = blockIdx.z >> 2, chunk = blockIdx.z & 3;
    const float* sc_g = side ? fg_score : cls_score;
    const short* base = qkv + (long)side * PN * PC3 + h * PD + q8;
    const short* qrow = base + (long)(row0 + wr + m16) * PC3;
    const short* kbase = base + PC;

    // Q fragments held in registers for all 4 col-tiles of this chunk
    bf16x8 a[4][4];
#pragma unroll
    for (int i = 0; i < 4; ++i)
#pragma unroll
        for (int kc = 0; kc < 4; ++kc)
            a[i][kc] = *(const bf16x8*)(qrow + (long)i * 16 * PC3 + kc * 32);

    float rs[4][4] = {};
    for (int ct = 0; ct < 4; ++ct) {
        const int ctg = chunk * 4 + ct;
        const short* krow = kbase + (long)(ctg * 128 + wc + m16) * PC3;
        f32x4 acc[4][4];
#pragma unroll
        for (int i = 0; i < 4; ++i)
#pragma unroll
            for (int j = 0; j < 4; ++j) acc[i][j] = (f32x4){0.f, 0.f, 0.f, 0.f};
#pragma unroll
        for (int kc = 0; kc < 4; ++kc) {
            bf16x8 b[4];
#pragma unroll
            for (int j = 0; j < 4; ++j)
                b[j] = *(const bf16x8*)(krow + (long)j * 16 * PC3 + kc * 32);
#pragma unroll
            for (int i = 0; i < 4; ++i)
#pragma unroll
                for (int j = 0; j < 4; ++j)
                    acc[i][j] = __builtin_amdgcn_mfma_f32_16x16x32_bf16(a[i][kc], b[j], acc[i][j], 0, 0, 0);
        }
#pragma unroll
        for (int j = 0; j < 4; ++j) {
            const float s25 = 25.0f * sc_g[ctg * 128 + wc + j * 16 + m16];
#pragma unroll
            for (int i = 0; i < 4; ++i)
#pragma unroll
                for (int t = 0; t < 4; ++t)
                    rs[i][t] += __expf(acc[i][j][t] * s25);
        }
    }
#pragma unroll
    for (int i = 0; i < 4; ++i)
#pragma unroll
        for (int t = 0; t < 4; ++t) {
            float v = rs[i][t];
            v += __shfl_xor(v, 1, 64); v += __shfl_xor(v, 2, 64);
            v += __shfl_xor(v, 4, 64); v += __shfl_xor(v, 8, 64);
            if (m16 == 0) lsum[wr + i * 16 + q4 * 4 + t][wave & 1] = v;
        }
    __syncthreads();
    if (tid < 128)
        atomicAdd(&l_g[((long)side * PH + h) * PN + row0 + tid],
                  lsum[tid][0] + lsum[tid][1]);
}

// ---------------- attention kernel B: per-head attn tiles (NO LDS, no barriers) ----------------
// grid (16 col-tiles, 16 row-tiles, 8 heads); loops s={cls,reg} internally.
// Transposed MFMA (A=K,B=Q): lane holds 4 CONSECUTIVE attn COLUMNS -> s4v stores.
__global__ __launch_bounds__(256) void attn_combine_k(
    const short* __restrict__ qkv,
    const float* __restrict__ cls_score, const float* __restrict__ fg_score,
    const float* __restrict__ l_g,
    short* __restrict__ attn8)
{
    const int tid = threadIdx.x, wave = tid >> 6, lane = tid & 63;
    const int wr = (wave >> 1) * 64, wc = (wave & 1) * 64;
    const int m16 = lane & 15, q4 = lane >> 4, q8 = q4 * 8;
    const int col0 = blockIdx.x * 128, row0 = blockIdx.y * 128, h = blockIdx.z;
    const long NN = (long)PN * PN;

    f32x4 comb[4][4];

#pragma unroll
    for (int s = 0; s < 2; ++s) {
        const short* base = qkv + (long)s * PN * PC3 + h * PD + q8;
        const short* qrow = base + (long)(row0 + wr + m16) * PC3;
        const short* krow = base + PC + (long)(col0 + wc + m16) * PC3;

        float rl[4];
#pragma unroll
        for (int j = 0; j < 4; ++j)
            rl[j] = 0.5f / l_g[((long)s * PH + h) * PN + row0 + wr + j * 16 + m16];

        f32x4 acc[4][4];
#pragma unroll
        for (int i = 0; i < 4; ++i)
#pragma unroll
            for (int j = 0; j < 4; ++j) acc[i][j] = (f32x4){0.f, 0.f, 0.f, 0.f};
#pragma unroll
        for (int kc = 0; kc < 4; ++kc) {
            bf16x8 kf[4], qf[4];
#pragma unroll
            for (int i = 0; i < 4; ++i)
                kf[i] = *(const bf16x8*)(krow + (long)i * 16 * PC3 + kc * 32);
#pragma unroll
            for (int j = 0; j < 4; ++j)
                qf[j] = *(const bf16x8*)(qrow + (long)j * 16 * PC3 + kc * 32);
#pragma unroll
            for (int i = 0; i < 4; ++i)
#pragma unroll
                for (int j = 0; j < 4; ++j)
                    acc[i][j] = __builtin_amdgcn_mfma_f32_16x16x32_bf16(kf[i], qf[j], acc[i][j], 0, 0, 0);
        }
        const float* sc_g = s ? fg_score : cls_score;
#pragma unroll
        for (int i = 0; i < 4; ++i) {
            const f32x4 sc4 = *(const f32x4*)&sc_g[col0 + wc + i * 16 + q4 * 4];
#pragma unroll
            for (int j = 0; j < 4; ++j)
#pragma unroll
                for (int t = 0; t < 4; ++t) {
                    const float e = __expf(acc[i][j][t] * (25.0f * sc4[t])) * rl[j];
                    comb[i][j][t] = s ? (comb[i][j][t] + e) : e;
                }
        }
    }
#pragma unroll
    for (int j = 0; j < 4; ++j) {
        const long rb = (long)h * NN + (long)(row0 + wr + j * 16 + m16) * PN
                      + col0 + wc + q4 * 4;
#pragma unroll
        for (int i = 0; i < 4; ++i) {
            s4v o;
#pragma unroll
            for (int t = 0; t < 4; ++t) o[t] = f2bf(comb[i][j][t]);
            *(s4v*)&attn8[rb + i * 16] = o;
        }
    }
}

// ---------------- fused fp32 -> bf16 convert (6 segments, contiguous dst) ----------------
// total float4s = 512K+512K+768K+768K+1024K+1024K = 4,718,592  -> 18432 blocks x 256
__global__ __launch_bounds__(256) void f2bf6_k(
    const float* __restrict__ s0, const float* __restrict__ s1,
    const float* __restrict__ s2, const float* __restrict__ s3,
    const float* __restrict__ s4, const float* __restrict__ s5,
    short* __restrict__ dst)
{
    const int n0 = 512 * 1024, n1 = 512 * 1024, n2 = 768 * 1024,
              n3 = 768 * 1024, n4 = 1024 * 1024;
    const int i = blockIdx.x * 256 + threadIdx.x;
    const float* src;
    int j = i;
    if (j < n0) src = s0;
    else { j -= n0; if (j < n1) src = s1;
    else { j -= n1; if (j < n2) src = s2;
    else { j -= n2; if (j < n3) src = s3;
    else { j -= n3; if (j < n4) src = s4;
    else { j -= n4; src = s5; } } } } }
    float4 v = ((const float4*)src)[j];
    s4v o;
    o[0] = f2bf(v.x); o[1] = f2bf(v.y); o[2] = f2bf(v.z); o[3] = f2bf(v.w);
    ((s4v*)dst)[i] = o;
}

// ---------------- bf16 tiled transpose ----------------
__global__ __launch_bounds__(256) void transpose_bf16_k(
    const short* __restrict__ src, int sld, short* __restrict__ dst, int dld)
{
    __shared__ short tl[64][72];
    const int r0 = blockIdx.y * 64, c0 = blockIdx.x * 64;
    const int tr = threadIdx.x >> 2;
    const int tc = (threadIdx.x & 3) * 16;
    const short* sp = src + (long)(r0 + tr) * sld + c0 + tc;
    s8v v0 = *(const s8v*)sp;
    s8v v1 = *(const s8v*)(sp + 8);
    *(s8v*)&tl[tr][tc] = v0;
    *(s8v*)&tl[tr][tc + 8] = v1;
    __syncthreads();
    s8v o0, o1;
#pragma unroll
    for (int k = 0; k < 8; ++k) { o0[k] = tl[tc + k][tr]; o1[k] = tl[tc + 8 + k][tr]; }
    short* dp = dst + (long)(c0 + tr) * dld + r0 + tc;
    *(s8v*)dp = o0;
    *(s8v*)(dp + 8) = o1;
}

// ---------------- merged L2 norms: y=0..3 -> {cls,reg}x{q,k}; y=4 -> v path ----------------
__global__ __launch_bounds__(256) void norms_k(short* __restrict__ qkv,
                                               short* __restrict__ Vn,
                                               short* __restrict__ trans)
{
    const int n = blockIdx.x, which = blockIdx.y, t = threadIdx.x;
    if (which < 4) {
        short* p = qkv + (long)(which >> 1) * ((long)PN * PC3)
                 + (long)n * PC3 + (which & 1) * PC + t * 4;
        s4v v = *(s4v*)p;
        float f0 = bf2f(v[0]), f1 = bf2f(v[1]), f2 = bf2f(v[2]), f3 = bf2f(v[3]);
        float ss = f0 * f0 + f1 * f1 + f2 * f2 + f3 * f3;
        ss += __shfl_xor(ss, 16, 64); ss += __shfl_xor(ss, 8, 64);
        ss += __shfl_xor(ss, 4, 64);  ss += __shfl_xor(ss, 2, 64);
        ss += __shfl_xor(ss, 1, 64);
        const float rn = rsqrtf(ss);
        s4v o;
        o[0] = f2bf(f0 * rn); o[1] = f2bf(f1 * rn);
        o[2] = f2bf(f2 * rn); o[3] = f2bf(f3 * rn);
        *(s4v*)p = o;
    } else {
        const short* p = qkv + (long)n * PC3 + 2 * PC + t * 4;
        s4v v = *(const s4v*)p;
        float f0 = bf2f(v[0]), f1 = bf2f(v[1]), f2 = bf2f(v[2]), f3 = bf2f(v[3]);
        float ss = f0 * f0 + f1 * f1 + f2 * f2 + f3 * f3;
        ss += __shfl_xor(ss, 16, 64); ss += __shfl_xor(ss, 8, 64);
        ss += __shfl_xor(ss, 4, 64);  ss += __shfl_xor(ss, 2, 64);
        ss += __shfl_xor(ss, 1, 64);
        const float rn = rsqrtf(ss);
        s4v o;
        o[0] = f2bf(f0 * rn); o[1] = f2bf(f1 * rn);
        o[2] = f2bf(f2 * rn); o[3] = f2bf(f3 * rn);
        *(s4v*)(Vn + (long)n * PC + t * 4) = o;
        *(s4v*)(trans + (long)n * (2 * PC) + PC + t * 4) = v;
    }
}

// ---------------- reductions ----------------
__device__ __forceinline__ float wave_sum(float v) {
#pragma unroll
    for (int o = 32; o > 0; o >>= 1) v += __shfl_xor(v, o, 64);
    return v;
}
__device__ __forceinline__ float wave_max(float v) {
#pragma unroll
    for (int o = 32; o > 0; o >>= 1) v = fmaxf(v, __shfl_xor(v, o, 64));
    return v;
}
__device__ __forceinline__ float block_sum(float v, float* sm) {
    v = wave_sum(v);
    __syncthreads();
    if ((threadIdx.x & 63) == 0) sm[threadIdx.x >> 6] = v;
    __syncthreads();
    return sm[0] + sm[1] + sm[2] + sm[3];
}
__device__ __forceinline__ float block_max(float v, float* sm) {
    v = wave_max(v);
    __syncthreads();
    if ((threadIdx.x & 63) == 0) sm[threadIdx.x >> 6] = v;
    __syncthreads();
    return fmaxf(fmaxf(sm[0], sm[1]), fmaxf(sm[2], sm[3]));
}

// ---------------- sim_round2: sum attn8 over heads, softmax, mask, renorm ----------------
// one block per row; thread t handles cols [8t, 8t+8)
__global__ __launch_bounds__(256) void sim_round2_k(
    const short* __restrict__ attn8, const short* __restrict__ Sraw,
    short* __restrict__ Sout)
{
    __shared__ float sm[4];
    const long NN = (long)PN * PN;
    const long rowoff = (long)blockIdx.x * PN + threadIdx.x * 8;
    float v[8] = {0.f, 0.f, 0.f, 0.f, 0.f, 0.f, 0.f, 0.f};
#pragma unroll
    for (int h = 0; h < PH; ++h) {
        s8v a = *(const s8v*)&attn8[(long)h * NN + rowoff];
#pragma unroll
        for (int j = 0; j < 8; ++j) v[j] += bf2f(a[j]);
    }
    bool keep[8];
    {
        s8v raw = *(const s8v*)&Sraw[rowoff];
#pragma unroll
        for (int j = 0; j < 8; ++j) {
            v[j] *= 0.125f;
            keep[j] = bf2f(raw[j]) > 0.75f;
        }
    }
    float mx = -1e30f;
#pragma unroll
    for (int j = 0; j < 8; ++j) mx = fmaxf(mx, v[j]);
    mx = block_max(mx, sm);
    float sum = 0.f;
#pragma unroll
    for (int j = 0; j < 8; ++j) { v[j] = __expf(v[j] - mx); sum += v[j]; }
    sum = block_sum(sum, sm);
    const float inv = 1.0f / sum;
    float msum = 0.f;
#pragma unroll
    for (int j = 0; j < 8; ++j) { v[j] = keep[j] ? v[j] * inv : 0.f; msum += v[j]; }
    msum = block_sum(msum, sm);
    const float minv = 1.0f / msum;
    s8v o;
#pragma unroll
    for (int j = 0; j < 8; ++j) o[j] = f2bf(v[j] * minv);
    *(s8v*)&Sout[rowoff] = o;
}

// ---------------- host ----------------
extern "C" void kernel_launch(void* const* d_in, const int* in_sizes, int n_in,
                              void* d_out, int out_size, void* d_ws, size_t ws_size,
                              hipStream_t stream)
{
    (void)in_sizes; (void)n_in; (void)out_size; (void)ws_size;
    const float* x_cls = (const float*)d_in[0];
    const float* x_reg = (const float*)d_in[1];
    const float* cls_score = (const float*)d_in[2];
    const float* fg_score = (const float*)d_in[3];
    const float* Wqc = (const float*)d_in[4];
    const float* Wqr = (const float*)d_in[5];
    const float* W1 = (const float*)d_in[6];
    const float* b1 = (const float*)d_in[7];
    const float* W2 = (const float*)d_in[8];
    const float* b2 = (const float*)d_in[9];
    float* out = (float*)d_out;

    // ---- workspace (MiB offsets), peak ~156.2 MiB ----
    char* w = (char*)d_ws;
    short* qkv_cls_bf = (short*)(w + ((size_t)0   << 20)); // 12 MiB [N,3C]
    short* qkv_reg_bf = (short*)(w + ((size_t)12  << 20)); // 12 MiB (adjacent)
    short* attn8      = (short*)(w + ((size_t)24  << 20)); // 64 MiB [8][N,N] bf16
    short* sim_bf     = (short*)(w + ((size_t)88  << 20)); // 8 MiB (own region)
    short* sim_raw_bf = (short*)(w + ((size_t)104 << 20)); // 8 MiB
    short* Vn         = (short*)(w + ((size_t)112 << 20)); // 4 MiB
    short* vT         = (short*)(w + ((size_t)116 << 20)); // 4 MiB [C,N]
    short* bf_all     = (short*)(w + ((size_t)120 << 20)); // 36 MiB contiguous:
    short* x_cls_bf   = bf_all;                            //  @120, 4 MiB
    short* x_reg_bf   = (short*)(w + ((size_t)124 << 20)); //  4 MiB
    short* Wqc_bf     = (short*)(w + ((size_t)128 << 20)); //  6 MiB
    short* Wqr_bf     = (short*)(w + ((size_t)134 << 20)); //  6 MiB
    short* W1_bf      = (short*)(w + ((size_t)140 << 20)); //  8 MiB
    short* W2_bf      = (short*)(w + ((size_t)148 << 20)); //  8 MiB (ends 156)
    float* l_g        = (float*)(w + ((size_t)156 << 20)); // 128 KiB [2][8][N]
    // overlays (written only after their underlying buffers are dead):
    short* trans      = (short*)(w + ((size_t)120 << 20)); // 8 MiB over x_* (post-QKV)
    short* featT      = (short*)(w + ((size_t)32  << 20)); // 8 MiB over attn8[1] (post round2)
    short* ave        = (short*)(w + ((size_t)40  << 20)); // 16 MiB over attn8[2..3]

    const long NN = (long)PN * PN;

    // ---- fused fp32 -> bf16 (one launch; dst = bf_all contiguous) ----
    f2bf6_k<<<18432, 256, 0, stream>>>(x_cls, x_reg, Wqc, Wqr, W1, W2, bf_all);

    // ---- QKV projections ----
    mfma_gemm_k<128, true, false><<<dim3(24, 16, 1), 256, 0, stream>>>(
        x_cls_bf, PC, 0, Wqc_bf, PC, 0, qkv_cls_bf, PC3, 0, PC, 1.0f, nullptr);
    mfma_gemm_k<128, true, false><<<dim3(16, 16, 1), 256, 0, stream>>>(  // q,k only
        x_reg_bf, PC, 0, Wqr_bf, PC, 0, qkv_reg_bf, PC3, 0, PC, 1.0f, nullptr);

    // ---- all norms in one launch; v transpose ----
    norms_k<<<dim3(PN, 5), 256, 0, stream>>>(qkv_cls_bf, Vn, trans);
    transpose_bf16_k<<<dim3(PC / 64, PN / 64), 256, 0, stream>>>(
        qkv_cls_bf + 2 * PC, PC3, vT, PN);

    // ---- sim_raw = (Vn @ Vn^T)/H, one K=1024 GEMM ----
    mfma_gemm_k<128, true, false><<<dim3(16, 16, 1), 256, 0, stream>>>(
        Vn, PC, 0, Vn, PC, 0, sim_raw_bf, PN, 0, PC, 0.125f, nullptr);

    // ---- fused attention: row sums (atomic over col chunks), then per-head tiles ----
    hipMemsetAsync(l_g, 0, (size_t)2 * PH * PN * sizeof(float), stream);
    attn_rowsum_k<<<dim3(16, PH, 8), 256, 0, stream>>>(
        qkv_cls_bf, cls_score, fg_score, l_g);
    attn_combine_k<<<dim3(16, 16, PH), 256, 0, stream>>>(
        qkv_cls_bf, cls_score, fg_score, l_g, attn8);

    // ---- x = attn @ v, all 8 heads z-batched ----
    mfma_gemm_k<64, true, false><<<dim3(2, 16, PH), 256, 0, stream>>>(
        attn8, PN, NN, vT, PN, (long)PD * PN, trans, 2 * PC, PD, PN, 1.0f, nullptr);

    // ---- sim_round2 (reads attn8 directly; head-sum folded in) ----
    sim_round2_k<<<PN, 256, 0, stream>>>(attn8, sim_raw_bf, sim_bf);

    // ---- msa/feat = trans @ W1^T + b1 -> ave cols [2C,4C) ----
    mfma_gemm_k<128, true, true><<<dim3(16, 16, 1), 256, 0, stream>>>(
        trans, 2 * PC, 0, W1_bf, 2 * PC, 0, ave + 2 * PC, 4 * PC, 0, 2 * PC, 1.0f, b1);

    // ---- featT = feat^T ----
    transpose_bf16_k<<<dim3(32, 32), 256, 0, stream>>>(ave + 2 * PC, 4 * PC, featT, 2 * PC);

    // ---- soft_sim = sim_round2 @ feat -> ave cols [0,2C) ----
    mfma_gemm_k<128, true, false><<<dim3(16, 16, 1), 256, 0, stream>>>(
        sim_bf, 2 * PC, 0, featT, 2 * PC, 0, ave, 4 * PC, 0, 2 * PC, 1.0f, nullptr);

    // ---- out = ave @ W2^T + b2 ----
    mfma_gemm_k<64, false, true><<<dim3(16, 16, 1), 256, 0, stream>>>(
        ave, 4 * PC, 0, W2_bf, 4 * PC, 0, out, PC, 0, 4 * PC, 1.0f, b2);
}

// Round 8
// 460.695 us; speedup vs baseline: 1.2007x; 1.2007x over previous
//
#include <hip/hip_runtime.h>
#include <math.h>

#define PN 2048
#define PC 1024
#define PH 8
#define PD 128
#define PC3 3072

typedef __bf16 bf16x8 __attribute__((ext_vector_type(8)));
typedef float  f32x4  __attribute__((ext_vector_type(4)));
typedef short  s8v    __attribute__((ext_vector_type(8)));
typedef short  s4v    __attribute__((ext_vector_type(4)));

__device__ __forceinline__ short f2bf(float x) {
    unsigned u = __float_as_uint(x);
    unsigned r = (u + 0x7fffu + ((u >> 16) & 1u)) >> 16;
    return (short)r;
}
__device__ __forceinline__ float bf2f(short s) {
    return __uint_as_float(((unsigned)(unsigned short)s) << 16);
}

#define LDS_DMA(g, l) __builtin_amdgcn_global_load_lds( \
    (const __attribute__((address_space(1))) void*)(g), \
    (__attribute__((address_space(3))) void*)(l), 16, 0, 0)

// stage a [128 rows][128 cols] bf16 tile into LDS as 4 [128][32] panels
__device__ __forceinline__ void stage128(const short* g, long ld, short* lds,
                                         int wave, int lrow, int lcol)
{
#pragma unroll
    for (int kc = 0; kc < 4; ++kc) {
        LDS_DMA(g + (long)lrow * ld + kc * 32 + lcol, lds + kc * 4096 + wave * 512);
        LDS_DMA(g + (long)(lrow + 64) * ld + kc * 32 + lcol,
                lds + kc * 4096 + 2048 + wave * 512);
    }
}

// ---------------- bf16 MFMA GEMM:  C = alpha * A @ B^T (+bias) (+transposed bf16 acc) ----
// BM in {64,128}, BN in {64,128}. grid x = N/BN, y = M/BM, z batched by strides.
template<int BM, int BN, bool OBF16, bool BIAS, bool ACCT>
__global__ __launch_bounds__(256) void mfma_gemm_k(
    const short* __restrict__ A, int lda, long zsa,
    const short* __restrict__ B, int ldb, long zsb,
    void* __restrict__ Cv, int ldc, long zsc,
    int K, float alpha, const float* __restrict__ bias,
    const short* __restrict__ accT, int ldat)
{
    constexpr int NI = BM / 32, NJ = BN / 32;
    __shared__ short As[BM * 32];
    __shared__ short Bs[BN * 32];
    const int tid = threadIdx.x;
    const int wave = tid >> 6, lane = tid & 63;
    const int lrow = tid >> 2;
    const int lcol = (tid & 3) * 8;
    const int z = blockIdx.z;
    A += (long)z * zsa;
    B += (long)z * zsb;
    const int row0 = blockIdx.y * BM, col0 = blockIdx.x * BN;
    const short* Ag = A + (long)(row0 + lrow) * lda + lcol;
    const short* Bg = B + (long)(col0 + lrow) * ldb + lcol;
    const int wr = (wave >> 1) * (BM / 2), wc = (wave & 1) * (BN / 2);
    const int m16 = lane & 15, q4 = lane >> 4, q8 = q4 * 8;

    f32x4 acc[NI][NJ];
#pragma unroll
    for (int i = 0; i < NI; ++i)
#pragma unroll
        for (int j = 0; j < NJ; ++j) acc[i][j] = (f32x4){0.f, 0.f, 0.f, 0.f};

    for (int kt = 0; kt < K; kt += 32) {
        if (kt) __syncthreads();
        LDS_DMA(Ag + kt, As + wave * 512);
        if (BM == 128) LDS_DMA(Ag + kt + 64 * (long)lda, As + 2048 + wave * 512);
        LDS_DMA(Bg + kt, Bs + wave * 512);
        if (BN == 128) LDS_DMA(Bg + kt + 64 * (long)ldb, Bs + 2048 + wave * 512);
        __syncthreads();
        bf16x8 a[NI], b[NJ];
#pragma unroll
        for (int i = 0; i < NI; ++i)
            a[i] = *(const bf16x8*)&As[(wr + i * 16 + m16) * 32 + q8];
#pragma unroll
        for (int j = 0; j < NJ; ++j)
            b[j] = *(const bf16x8*)&Bs[(wc + j * 16 + m16) * 32 + q8];
#pragma unroll
        for (int i = 0; i < NI; ++i)
#pragma unroll
            for (int j = 0; j < NJ; ++j)
                acc[i][j] = __builtin_amdgcn_mfma_f32_16x16x32_bf16(a[i], b[j], acc[i][j], 0, 0, 0);
    }

    const long cz = (long)z * zsc;
#pragma unroll
    for (int i = 0; i < NI; ++i) {
        const int r0 = row0 + wr + i * 16 + q4 * 4;
#pragma unroll
        for (int j = 0; j < NJ; ++j) {
            const int c = col0 + wc + j * 16 + m16;
            const float bv = BIAS ? bias[c] : 0.0f;
            s4v av;
            if (ACCT) av = *(const s4v*)&accT[(long)c * ldat + r0];
#pragma unroll
            for (int t = 0; t < 4; ++t) {
                float x = acc[i][j][t] * alpha + bv;
                if (ACCT) x += bf2f(av[t]);
                const long off = cz + (long)(r0 + t) * ldc + c;
                if (OBF16) ((short*)Cv)[off] = f2bf(x);
                else       ((float*)Cv)[off] = x;
            }
        }
    }
}

// ---------------- attention kernel A: softmax row sums (round-6 LDS version) ----------------
__global__ __launch_bounds__(256) void attn_rowsum_k(
    const short* __restrict__ qkv,
    const float* __restrict__ cls_score, const float* __restrict__ fg_score,
    float* __restrict__ l_g)
{
    __shared__ short Qs[16384];
    __shared__ short Ks[16384];
    __shared__ float lsum[128][2];
    const int tid = threadIdx.x, wave = tid >> 6, lane = tid & 63;
    const int lrow = tid >> 2, lcol = (tid & 3) * 8;
    const int wr = (wave >> 1) * 64, wc = (wave & 1) * 64;
    const int m16 = lane & 15, q4 = lane >> 4, q8 = q4 * 8;
    const int row0 = blockIdx.x * 128, h = blockIdx.y;
    const int side = blockIdx.z >> 2, chunk = blockIdx.z & 3;
    const float* sc_g = side ? fg_score : cls_score;
    const short* base = qkv + (long)side * PN * PC3 + h * PD;
    const short* Kg = base + PC;
    stage128(base + (long)row0 * PC3, PC3, Qs, wave, lrow, lcol);
    stage128(Kg + (long)chunk * 4 * 128 * PC3, PC3, Ks, wave, lrow, lcol);
    __syncthreads();
    bf16x8 a[4][4];
#pragma unroll
    for (int i = 0; i < 4; ++i)
#pragma unroll
        for (int kc = 0; kc < 4; ++kc)
            a[i][kc] = *(const bf16x8*)&Qs[kc * 4096 + (wr + i * 16 + m16) * 32 + q8];
    float rs[4][4] = {};
    for (int ct = 0; ct < 4; ++ct) {
        const int ctg = chunk * 4 + ct;
        if (ct) {
            __syncthreads();
            stage128(Kg + (long)ctg * 128 * PC3, PC3, Ks, wave, lrow, lcol);
            __syncthreads();
        }
        f32x4 acc[4][4];
#pragma unroll
        for (int i = 0; i < 4; ++i)
#pragma unroll
            for (int j = 0; j < 4; ++j) acc[i][j] = (f32x4){0.f, 0.f, 0.f, 0.f};
#pragma unroll
        for (int kc = 0; kc < 4; ++kc) {
            bf16x8 b[4];
#pragma unroll
            for (int j = 0; j < 4; ++j)
                b[j] = *(const bf16x8*)&Ks[kc * 4096 + (wc + j * 16 + m16) * 32 + q8];
#pragma unroll
            for (int i = 0; i < 4; ++i)
#pragma unroll
                for (int j = 0; j < 4; ++j)
                    acc[i][j] = __builtin_amdgcn_mfma_f32_16x16x32_bf16(a[i][kc], b[j], acc[i][j], 0, 0, 0);
        }
#pragma unroll
        for (int j = 0; j < 4; ++j) {
            const float s25 = 25.0f * sc_g[ctg * 128 + wc + j * 16 + m16];
#pragma unroll
            for (int i = 0; i < 4; ++i)
#pragma unroll
                for (int t = 0; t < 4; ++t)
                    rs[i][t] += __expf(acc[i][j][t] * s25);
        }
    }
#pragma unroll
    for (int i = 0; i < 4; ++i)
#pragma unroll
        for (int t = 0; t < 4; ++t) {
            float v = rs[i][t];
            v += __shfl_xor(v, 1, 64); v += __shfl_xor(v, 2, 64);
            v += __shfl_xor(v, 4, 64); v += __shfl_xor(v, 8, 64);
            if (m16 == 0) lsum[wr + i * 16 + q4 * 4 + t][wave & 1] = v;
        }
    __syncthreads();
    if (tid < 128)
        atomicAdd(&l_g[((long)side * PH + h) * PN + row0 + tid],
                  lsum[tid][0] + lsum[tid][1]);
}

// ---------------- attention kernel B: per-head attn tiles (round-6 LDS version) ----------------
__global__ __launch_bounds__(256) void attn_combine_k(
    const short* __restrict__ qkv,
    const float* __restrict__ cls_score, const float* __restrict__ fg_score,
    const float* __restrict__ l_g,
    short* __restrict__ attn8)
{
    __shared__ short Ts[32768];
    const int tid = threadIdx.x, wave = tid >> 6, lane = tid & 63;
    const int lrow = tid >> 2, lcol = (tid & 3) * 8;
    const int wr = (wave >> 1) * 64, wc = (wave & 1) * 64;
    const int m16 = lane & 15, q4 = lane >> 4, q8 = q4 * 8;
    const int col0 = blockIdx.x * 128, row0 = blockIdx.y * 128, h = blockIdx.z;
    const long NN = (long)PN * PN;

    f32x4 comb[4][4];

#pragma unroll
    for (int s = 0; s < 2; ++s) {
        const short* bq = qkv + (long)s * PN * PC3 + h * PD;
        __syncthreads();
        stage128(bq + (long)row0 * PC3, PC3, Ts, wave, lrow, lcol);
        stage128(bq + PC + (long)col0 * PC3, PC3, Ts + 16384, wave, lrow, lcol);
        __syncthreads();

        float rl[4];
#pragma unroll
        for (int j = 0; j < 4; ++j)
            rl[j] = 0.5f / l_g[((long)s * PH + h) * PN + row0 + wr + j * 16 + m16];

        f32x4 acc[4][4];
#pragma unroll
        for (int i = 0; i < 4; ++i)
#pragma unroll
            for (int j = 0; j < 4; ++j) acc[i][j] = (f32x4){0.f, 0.f, 0.f, 0.f};
#pragma unroll
        for (int kc = 0; kc < 4; ++kc) {
            bf16x8 kf[4], qf[4];
#pragma unroll
            for (int i = 0; i < 4; ++i)
                kf[i] = *(const bf16x8*)&Ts[16384 + kc * 4096 + (wc + i * 16 + m16) * 32 + q8];
#pragma unroll
            for (int j = 0; j < 4; ++j)
                qf[j] = *(const bf16x8*)&Ts[kc * 4096 + (wr + j * 16 + m16) * 32 + q8];
#pragma unroll
            for (int i = 0; i < 4; ++i)
#pragma unroll
                for (int j = 0; j < 4; ++j)
                    acc[i][j] = __builtin_amdgcn_mfma_f32_16x16x32_bf16(kf[i], qf[j], acc[i][j], 0, 0, 0);
        }
        const float* sc_g = s ? fg_score : cls_score;
#pragma unroll
        for (int i = 0; i < 4; ++i) {
            const f32x4 sc4 = *(const f32x4*)&sc_g[col0 + wc + i * 16 + q4 * 4];
#pragma unroll
            for (int j = 0; j < 4; ++j)
#pragma unroll
                for (int t = 0; t < 4; ++t) {
                    const float e = __expf(acc[i][j][t] * (25.0f * sc4[t])) * rl[j];
                    comb[i][j][t] = s ? (comb[i][j][t] + e) : e;
                }
        }
    }
#pragma unroll
    for (int j = 0; j < 4; ++j) {
        const long rb = (long)h * NN + (long)(row0 + wr + j * 16 + m16) * PN
                      + col0 + wc + q4 * 4;
#pragma unroll
        for (int i = 0; i < 4; ++i) {
            s4v o;
#pragma unroll
            for (int t = 0; t < 4; ++t) o[t] = f2bf(comb[i][j][t]);
            *(s4v*)&attn8[rb + i * 16] = o;
        }
    }
}

// ---------------- fused fp32 -> bf16 convert; W2 segment packed to W2p ----------------
// W2p[d,c]=W2[d,c] (d<1024); W2p[1024+d,c]=W2[d,2048+c].  18432 blocks x 256.
__global__ __launch_bounds__(256) void f2bf6_k(
    const float* __restrict__ s0, const float* __restrict__ s1,
    const float* __restrict__ s2, const float* __restrict__ s3,
    const float* __restrict__ s4, const float* __restrict__ s5,
    short* __restrict__ dst)
{
    const int n0 = 512 * 1024, n1 = 512 * 1024, n2 = 768 * 1024,
              n3 = 768 * 1024, n4 = 1024 * 1024;
    const int i = blockIdx.x * 256 + threadIdx.x;
    const float* src;
    int j = i;
    bool w2 = false;
    if (j < n0) src = s0;
    else { j -= n0; if (j < n1) src = s1;
    else { j -= n1; if (j < n2) src = s2;
    else { j -= n2; if (j < n3) src = s3;
    else { j -= n3; if (j < n4) src = s4;
    else { j -= n4; src = s5; w2 = true; } } } } }
    float4 v = ((const float4*)src)[j];
    s4v o;
    o[0] = f2bf(v.x); o[1] = f2bf(v.y); o[2] = f2bf(v.z); o[3] = f2bf(v.w);
    long oj = i;
    if (w2) {
        const int e = j << 2;
        const int d = e >> 12, c = e & 4095;
        const long pe = (c < 2048) ? ((long)d * 2048 + c)
                                   : ((long)(1024 + d) * 2048 + (c - 2048));
        oj = (long)(3584 * 1024) + (pe >> 2);
    }
    ((s4v*)dst)[oj] = o;
}

// ---------------- bf16 tiled transpose ----------------
__global__ __launch_bounds__(256) void transpose_bf16_k(
    const short* __restrict__ src, int sld, short* __restrict__ dst, int dld)
{
    __shared__ short tl[64][72];
    const int r0 = blockIdx.y * 64, c0 = blockIdx.x * 64;
    const int tr = threadIdx.x >> 2;
    const int tc = (threadIdx.x & 3) * 16;
    const short* sp = src + (long)(r0 + tr) * sld + c0 + tc;
    s8v v0 = *(const s8v*)sp;
    s8v v1 = *(const s8v*)(sp + 8);
    *(s8v*)&tl[tr][tc] = v0;
    *(s8v*)&tl[tr][tc + 8] = v1;
    __syncthreads();
    s8v o0, o1;
#pragma unroll
    for (int k = 0; k < 8; ++k) { o0[k] = tl[tc + k][tr]; o1[k] = tl[tc + 8 + k][tr]; }
    short* dp = dst + (long)(c0 + tr) * dld + r0 + tc;
    *(s8v*)dp = o0;
    *(s8v*)(dp + 8) = o1;
}

// ---------------- merged L2 norms ----------------
__global__ __launch_bounds__(256) void norms_k(short* __restrict__ qkv,
                                               short* __restrict__ Vn,
                                               short* __restrict__ trans)
{
    const int n = blockIdx.x, which = blockIdx.y, t = threadIdx.x;
    if (which < 4) {
        short* p = qkv + (long)(which >> 1) * ((long)PN * PC3)
                 + (long)n * PC3 + (which & 1) * PC + t * 4;
        s4v v = *(s4v*)p;
        float f0 = bf2f(v[0]), f1 = bf2f(v[1]), f2 = bf2f(v[2]), f3 = bf2f(v[3]);
        float ss = f0 * f0 + f1 * f1 + f2 * f2 + f3 * f3;
        ss += __shfl_xor(ss, 16, 64); ss += __shfl_xor(ss, 8, 64);
        ss += __shfl_xor(ss, 4, 64);  ss += __shfl_xor(ss, 2, 64);
        ss += __shfl_xor(ss, 1, 64);
        const float rn = rsqrtf(ss);
        s4v o;
        o[0] = f2bf(f0 * rn); o[1] = f2bf(f1 * rn);
        o[2] = f2bf(f2 * rn); o[3] = f2bf(f3 * rn);
        *(s4v*)p = o;
    } else {
        const short* p = qkv + (long)n * PC3 + 2 * PC + t * 4;
        s4v v = *(const s4v*)p;
        float f0 = bf2f(v[0]), f1 = bf2f(v[1]), f2 = bf2f(v[2]), f3 = bf2f(v[3]);
        float ss = f0 * f0 + f1 * f1 + f2 * f2 + f3 * f3;
        ss += __shfl_xor(ss, 16, 64); ss += __shfl_xor(ss, 8, 64);
        ss += __shfl_xor(ss, 4, 64);  ss += __shfl_xor(ss, 2, 64);
        ss += __shfl_xor(ss, 1, 64);
        const float rn = rsqrtf(ss);
        s4v o;
        o[0] = f2bf(f0 * rn); o[1] = f2bf(f1 * rn);
        o[2] = f2bf(f2 * rn); o[3] = f2bf(f3 * rn);
        *(s4v*)(Vn + (long)n * PC + t * 4) = o;
        *(s4v*)(trans + (long)n * (2 * PC) + PC + t * 4) = v;
    }
}

// ---------------- reductions ----------------
__device__ __forceinline__ float wave_sum(float v) {
#pragma unroll
    for (int o = 32; o > 0; o >>= 1) v += __shfl_xor(v, o, 64);
    return v;
}
__device__ __forceinline__ float wave_max(float v) {
#pragma unroll
    for (int o = 32; o > 0; o >>= 1) v = fmaxf(v, __shfl_xor(v, o, 64));
    return v;
}
__device__ __forceinline__ float block_sum(float v, float* sm) {
    v = wave_sum(v);
    __syncthreads();
    if ((threadIdx.x & 63) == 0) sm[threadIdx.x >> 6] = v;
    __syncthreads();
    return sm[0] + sm[1] + sm[2] + sm[3];
}
__device__ __forceinline__ float block_max(float v, float* sm) {
    v = wave_max(v);
    __syncthreads();
    if ((threadIdx.x & 63) == 0) sm[threadIdx.x >> 6] = v;
    __syncthreads();
    return fmaxf(fmaxf(sm[0], sm[1]), fmaxf(sm[2], sm[3]));
}

// ---------------- sim_round2: head-sum attn8, softmax, mask, renorm ----------------
__global__ __launch_bounds__(256) void sim_round2_k(
    const short* __restrict__ attn8, const short* __restrict__ Sraw,
    short* __restrict__ Sout)
{
    __shared__ float sm[4];
    const long NN = (long)PN * PN;
    const long rowoff = (long)blockIdx.x * PN + threadIdx.x * 8;
    float v[8] = {0.f, 0.f, 0.f, 0.f, 0.f, 0.f, 0.f, 0.f};
#pragma unroll
    for (int h = 0; h < PH; ++h) {
        s8v a = *(const s8v*)&attn8[(long)h * NN + rowoff];
#pragma unroll
        for (int j = 0; j < 8; ++j) v[j] += bf2f(a[j]);
    }
    bool keep[8];
    {
        s8v raw = *(const s8v*)&Sraw[rowoff];
#pragma unroll
        for (int j = 0; j < 8; ++j) {
            v[j] *= 0.125f;
            keep[j] = bf2f(raw[j]) > 0.75f;
        }
    }
    float mx = -1e30f;
#pragma unroll
    for (int j = 0; j < 8; ++j) mx = fmaxf(mx, v[j]);
    mx = block_max(mx, sm);
    float sum = 0.f;
#pragma unroll
    for (int j = 0; j < 8; ++j) { v[j] = __expf(v[j] - mx); sum += v[j]; }
    sum = block_sum(sum, sm);
    const float inv = 1.0f / sum;
    float msum = 0.f;
#pragma unroll
    for (int j = 0; j < 8; ++j) { v[j] = keep[j] ? v[j] * inv : 0.f; msum += v[j]; }
    msum = block_sum(msum, sm);
    const float minv = 1.0f / msum;
    s8v o;
#pragma unroll
    for (int j = 0; j < 8; ++j) o[j] = f2bf(v[j] * minv);
    *(s8v*)&Sout[rowoff] = o;
}

// ---------------- host ----------------
extern "C" void kernel_launch(void* const* d_in, const int* in_sizes, int n_in,
                              void* d_out, int out_size, void* d_ws, size_t ws_size,
                              hipStream_t stream)
{
    (void)in_sizes; (void)n_in; (void)out_size; (void)ws_size;
    const float* x_cls = (const float*)d_in[0];
    const float* x_reg = (const float*)d_in[1];
    const float* cls_score = (const float*)d_in[2];
    const float* fg_score = (const float*)d_in[3];
    const float* Wqc = (const float*)d_in[4];
    const float* Wqr = (const float*)d_in[5];
    const float* W1 = (const float*)d_in[6];
    const float* b1 = (const float*)d_in[7];
    const float* W2 = (const float*)d_in[8];
    const float* b2 = (const float*)d_in[9];
    float* out = (float*)d_out;

    // ---- workspace (MiB offsets), peak ~156.2 MiB ----
    char* w = (char*)d_ws;
    short* qkv_cls_bf = (short*)(w + ((size_t)0   << 20)); // 12 MiB [N,3C]
    short* qkv_reg_bf = (short*)(w + ((size_t)12  << 20)); // 12 MiB (adjacent)
    short* attn8      = (short*)(w + ((size_t)24  << 20)); // 64 MiB [8][N,N] bf16
    short* sim_bf     = (short*)(w + ((size_t)88  << 20)); // 8 MiB
    short* sim_raw_bf = (short*)(w + ((size_t)104 << 20)); // 8 MiB
    short* Vn         = (short*)(w + ((size_t)112 << 20)); // 4 MiB
    short* vT         = (short*)(w + ((size_t)116 << 20)); // 4 MiB [C,N]
    short* bf_all     = (short*)(w + ((size_t)120 << 20)); // 36 MiB contiguous:
    short* x_cls_bf   = bf_all;                            //  @120, 4 MiB (x_reg @124 adj)
    short* Wqc_bf     = (short*)(w + ((size_t)128 << 20)); //  6 MiB (Wqr @134 adj)
    short* W1_bf      = (short*)(w + ((size_t)140 << 20)); //  8 MiB
    short* W2p_bf     = (short*)(w + ((size_t)148 << 20)); //  8 MiB [2048,2048] packed
    float* l_g        = (float*)(w + ((size_t)156 << 20)); // 128 KiB [2][8][N]
    // overlays (after underlying dead):
    short* trans      = (short*)(w + ((size_t)120 << 20)); // 8 MiB over x_* (post-QKV)
    short* feat       = (short*)(w + ((size_t)24  << 20)); // 8 MiB over attn8[0] (post r2)
    short* UVt        = (short*)(w + ((size_t)32  << 20)); // 8 MiB over attn8[1]

    const long NN = (long)PN * PN;

    // ---- fused fp32 -> bf16 (W2 packed) ----
    f2bf6_k<<<18432, 256, 0, stream>>>(x_cls, x_reg, Wqc, Wqr, W1, W2, bf_all);

    // ---- QKV projections, merged z=2 (v_reg computed wastefully) ----
    mfma_gemm_k<128, 64, true, false, false><<<dim3(48, 16, 2), 256, 0, stream>>>(
        x_cls_bf, PC, (long)PN * PC, Wqc_bf, PC, (long)PC3 * PC,
        qkv_cls_bf, PC3, (long)PN * PC3, PC, 1.0f, nullptr, nullptr, 0);

    // ---- norms; v transpose ----
    norms_k<<<dim3(PN, 5), 256, 0, stream>>>(qkv_cls_bf, Vn, trans);
    transpose_bf16_k<<<dim3(PC / 64, PN / 64), 256, 0, stream>>>(
        qkv_cls_bf + 2 * PC, PC3, vT, PN);

    // ---- sim_raw = (Vn @ Vn^T)/H ----
    mfma_gemm_k<128, 64, true, false, false><<<dim3(32, 16, 1), 256, 0, stream>>>(
        Vn, PC, 0, Vn, PC, 0, sim_raw_bf, PN, 0, PC, 0.125f, nullptr, nullptr, 0);

    // ---- attention: row sums + per-head tiles ----
    hipMemsetAsync(l_g, 0, (size_t)2 * PH * PN * sizeof(float), stream);
    attn_rowsum_k<<<dim3(16, PH, 8), 256, 0, stream>>>(
        qkv_cls_bf, cls_score, fg_score, l_g);
    attn_combine_k<<<dim3(16, 16, PH), 256, 0, stream>>>(
        qkv_cls_bf, cls_score, fg_score, l_g, attn8);

    // ---- x = attn @ v, z=8, BM=64 for 512 blocks ----
    mfma_gemm_k<64, 64, true, false, false><<<dim3(2, 32, PH), 256, 0, stream>>>(
        attn8, PN, NN, vT, PN, (long)PD * PN, trans, 2 * PC, PD, PN, 1.0f,
        nullptr, nullptr, 0);

    // ---- sim_round2 (head-sum folded in) ----
    sim_round2_k<<<PN, 256, 0, stream>>>(attn8, sim_raw_bf, sim_bf);

    // ---- feat = trans @ W1^T + b1 (bf16, standalone buffer) ----
    mfma_gemm_k<128, 64, true, true, false><<<dim3(32, 16, 1), 256, 0, stream>>>(
        trans, 2 * PC, 0, W1_bf, 2 * PC, 0, feat, 2 * PC, 0, 2 * PC, 1.0f, b1,
        nullptr, 0);

    // ---- UVt = W2p @ feat^T : rows [0,1024)=U^T, [1024,2048)=V2^T ----
    mfma_gemm_k<128, 64, true, false, false><<<dim3(32, 16, 1), 256, 0, stream>>>(
        W2p_bf, 2 * PC, 0, feat, 2 * PC, 0, UVt, PN, 0, 2 * PC, 1.0f, nullptr,
        nullptr, 0);

    // ---- out = sim_bf @ (U^T)^T + V2 + b2 (transposed bf16 accumulate) ----
    mfma_gemm_k<128, 64, false, true, true><<<dim3(16, 16, 1), 256, 0, stream>>>(
        sim_bf, PN, 0, UVt, PN, 0, out, PC, 0, PN, 1.0f, b2,
        UVt + (long)PC * PN, PN);
}

// Round 9
// 431.172 us; speedup vs baseline: 1.2829x; 1.0685x over previous
//
#include <hip/hip_runtime.h>
#include <math.h>

#define PN 2048
#define PC 1024
#define PH 8
#define PD 128
#define PC3 3072

typedef __bf16 bf16x8 __attribute__((ext_vector_type(8)));
typedef float  f32x4  __attribute__((ext_vector_type(4)));
typedef short  s8v    __attribute__((ext_vector_type(8)));
typedef short  s4v    __attribute__((ext_vector_type(4)));

__device__ __forceinline__ short f2bf(float x) {
    unsigned u = __float_as_uint(x);
    unsigned r = (u + 0x7fffu + ((u >> 16) & 1u)) >> 16;
    return (short)r;
}
__device__ __forceinline__ float bf2f(short s) {
    return __uint_as_float(((unsigned)(unsigned short)s) << 16);
}

#define LDS_DMA(g, l) __builtin_amdgcn_global_load_lds( \
    (const __attribute__((address_space(1))) void*)(g), \
    (__attribute__((address_space(3))) void*)(l), 16, 0, 0)

// stage a [128 rows][128 cols] bf16 tile into LDS as 4 [128][32] panels
__device__ __forceinline__ void stage128(const short* g, long ld, short* lds,
                                         int wave, int lrow, int lcol)
{
#pragma unroll
    for (int kc = 0; kc < 4; ++kc) {
        LDS_DMA(g + (long)lrow * ld + kc * 32 + lcol, lds + kc * 4096 + wave * 512);
        LDS_DMA(g + (long)(lrow + 64) * ld + kc * 32 + lcol,
                lds + kc * 4096 + 2048 + wave * 512);
    }
}

// ---------------- bf16 MFMA GEMM:  C = alpha * A @ B^T (+bias) (+transposed bf16 acc) ----
// BM in {64,128}, BN in {64,128}. BK=64 (two 32-panels per barrier pair).
// K must be a multiple of 64. grid x = N/BN, y = M/BM, z batched by strides.
template<int BM, int BN, bool OBF16, bool BIAS, bool ACCT>
__global__ __launch_bounds__(256) void mfma_gemm_k(
    const short* __restrict__ A, int lda, long zsa,
    const short* __restrict__ B, int ldb, long zsb,
    void* __restrict__ Cv, int ldc, long zsc,
    int K, float alpha, const float* __restrict__ bias,
    const short* __restrict__ accT, int ldat)
{
    constexpr int NI = BM / 32, NJ = BN / 32;
    __shared__ short As[BM * 64];   // 2 panels of [BM][32]
    __shared__ short Bs[BN * 64];   // 2 panels of [BN][32]
    const int tid = threadIdx.x;
    const int wave = tid >> 6, lane = tid & 63;
    const int lrow = tid >> 2;
    const int lcol = (tid & 3) * 8;
    const int z = blockIdx.z;
    A += (long)z * zsa;
    B += (long)z * zsb;
    const int row0 = blockIdx.y * BM, col0 = blockIdx.x * BN;
    const short* Ag = A + (long)(row0 + lrow) * lda + lcol;
    const short* Bg = B + (long)(col0 + lrow) * ldb + lcol;
    const int wr = (wave >> 1) * (BM / 2), wc = (wave & 1) * (BN / 2);
    const int m16 = lane & 15, q4 = lane >> 4, q8 = q4 * 8;

    f32x4 acc[NI][NJ];
#pragma unroll
    for (int i = 0; i < NI; ++i)
#pragma unroll
        for (int j = 0; j < NJ; ++j) acc[i][j] = (f32x4){0.f, 0.f, 0.f, 0.f};

    for (int kt = 0; kt < K; kt += 64) {
        if (kt) __syncthreads();
        // panel 0 (k = kt..kt+32)
        LDS_DMA(Ag + kt, As + wave * 512);
        if (BM == 128) LDS_DMA(Ag + kt + 64 * (long)lda, As + 2048 + wave * 512);
        LDS_DMA(Bg + kt, Bs + wave * 512);
        if (BN == 128) LDS_DMA(Bg + kt + 64 * (long)ldb, Bs + 2048 + wave * 512);
        // panel 1 (k = kt+32..kt+64)
        LDS_DMA(Ag + kt + 32, As + BM * 32 + wave * 512);
        if (BM == 128) LDS_DMA(Ag + kt + 32 + 64 * (long)lda,
                               As + BM * 32 + 2048 + wave * 512);
        LDS_DMA(Bg + kt + 32, Bs + BN * 32 + wave * 512);
        if (BN == 128) LDS_DMA(Bg + kt + 32 + 64 * (long)ldb,
                               Bs + BN * 32 + 2048 + wave * 512);
        __syncthreads();
#pragma unroll
        for (int p = 0; p < 2; ++p) {
            bf16x8 a[NI], b[NJ];
#pragma unroll
            for (int i = 0; i < NI; ++i)
                a[i] = *(const bf16x8*)&As[p * BM * 32 + (wr + i * 16 + m16) * 32 + q8];
#pragma unroll
            for (int j = 0; j < NJ; ++j)
                b[j] = *(const bf16x8*)&Bs[p * BN * 32 + (wc + j * 16 + m16) * 32 + q8];
#pragma unroll
            for (int i = 0; i < NI; ++i)
#pragma unroll
                for (int j = 0; j < NJ; ++j)
                    acc[i][j] = __builtin_amdgcn_mfma_f32_16x16x32_bf16(a[i], b[j], acc[i][j], 0, 0, 0);
        }
    }

    const long cz = (long)z * zsc;
#pragma unroll
    for (int i = 0; i < NI; ++i) {
        const int r0 = row0 + wr + i * 16 + q4 * 4;
#pragma unroll
        for (int j = 0; j < NJ; ++j) {
            const int c = col0 + wc + j * 16 + m16;
            const float bv = BIAS ? bias[c] : 0.0f;
            s4v av;
            if (ACCT) av = *(const s4v*)&accT[(long)c * ldat + r0];
#pragma unroll
            for (int t = 0; t < 4; ++t) {
                float x = acc[i][j][t] * alpha + bv;
                if (ACCT) x += bf2f(av[t]);
                const long off = cz + (long)(r0 + t) * ldc + c;
                if (OBF16) ((short*)Cv)[off] = f2bf(x);
                else       ((float*)Cv)[off] = x;
            }
        }
    }
}

// ---------------- attention kernel A: softmax row sums ----------------
__global__ __launch_bounds__(256) void attn_rowsum_k(
    const short* __restrict__ qkv,
    const float* __restrict__ cls_score, const float* __restrict__ fg_score,
    float* __restrict__ l_g)
{
    __shared__ short Qs[16384];
    __shared__ short Ks[16384];
    __shared__ float lsum[128][2];
    const int tid = threadIdx.x, wave = tid >> 6, lane = tid & 63;
    const int lrow = tid >> 2, lcol = (tid & 3) * 8;
    const int wr = (wave >> 1) * 64, wc = (wave & 1) * 64;
    const int m16 = lane & 15, q4 = lane >> 4, q8 = q4 * 8;
    const int row0 = blockIdx.x * 128, h = blockIdx.y;
    const int side = blockIdx.z >> 2, chunk = blockIdx.z & 3;
    const float* sc_g = side ? fg_score : cls_score;
    const short* base = qkv + (long)side * PN * PC3 + h * PD;
    const short* Kg = base + PC;
    stage128(base + (long)row0 * PC3, PC3, Qs, wave, lrow, lcol);
    stage128(Kg + (long)chunk * 4 * 128 * PC3, PC3, Ks, wave, lrow, lcol);
    __syncthreads();
    bf16x8 a[4][4];
#pragma unroll
    for (int i = 0; i < 4; ++i)
#pragma unroll
        for (int kc = 0; kc < 4; ++kc)
            a[i][kc] = *(const bf16x8*)&Qs[kc * 4096 + (wr + i * 16 + m16) * 32 + q8];
    float rs[4][4] = {};
    for (int ct = 0; ct < 4; ++ct) {
        const int ctg = chunk * 4 + ct;
        if (ct) {
            __syncthreads();
            stage128(Kg + (long)ctg * 128 * PC3, PC3, Ks, wave, lrow, lcol);
            __syncthreads();
        }
        f32x4 acc[4][4];
#pragma unroll
        for (int i = 0; i < 4; ++i)
#pragma unroll
            for (int j = 0; j < 4; ++j) acc[i][j] = (f32x4){0.f, 0.f, 0.f, 0.f};
#pragma unroll
        for (int kc = 0; kc < 4; ++kc) {
            bf16x8 b[4];
#pragma unroll
            for (int j = 0; j < 4; ++j)
                b[j] = *(const bf16x8*)&Ks[kc * 4096 + (wc + j * 16 + m16) * 32 + q8];
#pragma unroll
            for (int i = 0; i < 4; ++i)
#pragma unroll
                for (int j = 0; j < 4; ++j)
                    acc[i][j] = __builtin_amdgcn_mfma_f32_16x16x32_bf16(a[i][kc], b[j], acc[i][j], 0, 0, 0);
        }
#pragma unroll
        for (int j = 0; j < 4; ++j) {
            const float s25 = 25.0f * sc_g[ctg * 128 + wc + j * 16 + m16];
#pragma unroll
            for (int i = 0; i < 4; ++i)
#pragma unroll
                for (int t = 0; t < 4; ++t)
                    rs[i][t] += __expf(acc[i][j][t] * s25);
        }
    }
#pragma unroll
    for (int i = 0; i < 4; ++i)
#pragma unroll
        for (int t = 0; t < 4; ++t) {
            float v = rs[i][t];
            v += __shfl_xor(v, 1, 64); v += __shfl_xor(v, 2, 64);
            v += __shfl_xor(v, 4, 64); v += __shfl_xor(v, 8, 64);
            if (m16 == 0) lsum[wr + i * 16 + q4 * 4 + t][wave & 1] = v;
        }
    __syncthreads();
    if (tid < 128)
        atomicAdd(&l_g[((long)side * PH + h) * PN + row0 + tid],
                  lsum[tid][0] + lsum[tid][1]);
}

// ---------------- attention kernel B: per-head attn tiles ----------------
__global__ __launch_bounds__(256) void attn_combine_k(
    const short* __restrict__ qkv,
    const float* __restrict__ cls_score, const float* __restrict__ fg_score,
    const float* __restrict__ l_g,
    short* __restrict__ attn8)
{
    __shared__ short Ts[32768];
    const int tid = threadIdx.x, wave = tid >> 6, lane = tid & 63;
    const int lrow = tid >> 2, lcol = (tid & 3) * 8;
    const int wr = (wave >> 1) * 64, wc = (wave & 1) * 64;
    const int m16 = lane & 15, q4 = lane >> 4, q8 = q4 * 8;
    const int col0 = blockIdx.x * 128, row0 = blockIdx.y * 128, h = blockIdx.z;
    const long NN = (long)PN * PN;

    f32x4 comb[4][4];

#pragma unroll
    for (int s = 0; s < 2; ++s) {
        const short* bq = qkv + (long)s * PN * PC3 + h * PD;
        __syncthreads();
        stage128(bq + (long)row0 * PC3, PC3, Ts, wave, lrow, lcol);
        stage128(bq + PC + (long)col0 * PC3, PC3, Ts + 16384, wave, lrow, lcol);
        __syncthreads();

        float rl[4];
#pragma unroll
        for (int j = 0; j < 4; ++j)
            rl[j] = 0.5f / l_g[((long)s * PH + h) * PN + row0 + wr + j * 16 + m16];

        f32x4 acc[4][4];
#pragma unroll
        for (int i = 0; i < 4; ++i)
#pragma unroll
            for (int j = 0; j < 4; ++j) acc[i][j] = (f32x4){0.f, 0.f, 0.f, 0.f};
#pragma unroll
        for (int kc = 0; kc < 4; ++kc) {
            bf16x8 kf[4], qf[4];
#pragma unroll
            for (int i = 0; i < 4; ++i)
                kf[i] = *(const bf16x8*)&Ts[16384 + kc * 4096 + (wc + i * 16 + m16) * 32 + q8];
#pragma unroll
            for (int j = 0; j < 4; ++j)
                qf[j] = *(const bf16x8*)&Ts[kc * 4096 + (wr + j * 16 + m16) * 32 + q8];
#pragma unroll
            for (int i = 0; i < 4; ++i)
#pragma unroll
                for (int j = 0; j < 4; ++j)
                    acc[i][j] = __builtin_amdgcn_mfma_f32_16x16x32_bf16(kf[i], qf[j], acc[i][j], 0, 0, 0);
        }
        const float* sc_g = s ? fg_score : cls_score;
#pragma unroll
        for (int i = 0; i < 4; ++i) {
            const f32x4 sc4 = *(const f32x4*)&sc_g[col0 + wc + i * 16 + q4 * 4];
#pragma unroll
            for (int j = 0; j < 4; ++j)
#pragma unroll
                for (int t = 0; t < 4; ++t) {
                    const float e = __expf(acc[i][j][t] * (25.0f * sc4[t])) * rl[j];
                    comb[i][j][t] = s ? (comb[i][j][t] + e) : e;
                }
        }
    }
#pragma unroll
    for (int j = 0; j < 4; ++j) {
        const long rb = (long)h * NN + (long)(row0 + wr + j * 16 + m16) * PN
                      + col0 + wc + q4 * 4;
#pragma unroll
        for (int i = 0; i < 4; ++i) {
            s4v o;
#pragma unroll
            for (int t = 0; t < 4; ++t) o[t] = f2bf(comb[i][j][t]);
            *(s4v*)&attn8[rb + i * 16] = o;
        }
    }
}

// ---------------- fused fp32 -> bf16 convert; W2 segment packed to W2p ----------------
__global__ __launch_bounds__(256) void f2bf6_k(
    const float* __restrict__ s0, const float* __restrict__ s1,
    const float* __restrict__ s2, const float* __restrict__ s3,
    const float* __restrict__ s4, const float* __restrict__ s5,
    short* __restrict__ dst)
{
    const int n0 = 512 * 1024, n1 = 512 * 1024, n2 = 768 * 1024,
              n3 = 768 * 1024, n4 = 1024 * 1024;
    const int i = blockIdx.x * 256 + threadIdx.x;
    const float* src;
    int j = i;
    bool w2 = false;
    if (j < n0) src = s0;
    else { j -= n0; if (j < n1) src = s1;
    else { j -= n1; if (j < n2) src = s2;
    else { j -= n2; if (j < n3) src = s3;
    else { j -= n3; if (j < n4) src = s4;
    else { j -= n4; src = s5; w2 = true; } } } } }
    float4 v = ((const float4*)src)[j];
    s4v o;
    o[0] = f2bf(v.x); o[1] = f2bf(v.y); o[2] = f2bf(v.z); o[3] = f2bf(v.w);
    long oj = i;
    if (w2) {
        const int e = j << 2;
        const int d = e >> 12, c = e & 4095;
        const long pe = (c < 2048) ? ((long)d * 2048 + c)
                                   : ((long)(1024 + d) * 2048 + (c - 2048));
        oj = (long)(3584 * 1024) + (pe >> 2);
    }
    ((s4v*)dst)[oj] = o;
}

// ---------------- bf16 tiled transpose ----------------
__global__ __launch_bounds__(256) void transpose_bf16_k(
    const short* __restrict__ src, int sld, short* __restrict__ dst, int dld)
{
    __shared__ short tl[64][72];
    const int r0 = blockIdx.y * 64, c0 = blockIdx.x * 64;
    const int tr = threadIdx.x >> 2;
    const int tc = (threadIdx.x & 3) * 16;
    const short* sp = src + (long)(r0 + tr) * sld + c0 + tc;
    s8v v0 = *(const s8v*)sp;
    s8v v1 = *(const s8v*)(sp + 8);
    *(s8v*)&tl[tr][tc] = v0;
    *(s8v*)&tl[tr][tc + 8] = v1;
    __syncthreads();
    s8v o0, o1;
#pragma unroll
    for (int k = 0; k < 8; ++k) { o0[k] = tl[tc + k][tr]; o1[k] = tl[tc + 8 + k][tr]; }
    short* dp = dst + (long)(c0 + tr) * dld + r0 + tc;
    *(s8v*)dp = o0;
    *(s8v*)(dp + 8) = o1;
}

// ---------------- merged L2 norms ----------------
__global__ __launch_bounds__(256) void norms_k(short* __restrict__ qkv,
                                               short* __restrict__ Vn,
                                               short* __restrict__ trans)
{
    const int n = blockIdx.x, which = blockIdx.y, t = threadIdx.x;
    if (which < 4) {
        short* p = qkv + (long)(which >> 1) * ((long)PN * PC3)
                 + (long)n * PC3 + (which & 1) * PC + t * 4;
        s4v v = *(s4v*)p;
        float f0 = bf2f(v[0]), f1 = bf2f(v[1]), f2 = bf2f(v[2]), f3 = bf2f(v[3]);
        float ss = f0 * f0 + f1 * f1 + f2 * f2 + f3 * f3;
        ss += __shfl_xor(ss, 16, 64); ss += __shfl_xor(ss, 8, 64);
        ss += __shfl_xor(ss, 4, 64);  ss += __shfl_xor(ss, 2, 64);
        ss += __shfl_xor(ss, 1, 64);
        const float rn = rsqrtf(ss);
        s4v o;
        o[0] = f2bf(f0 * rn); o[1] = f2bf(f1 * rn);
        o[2] = f2bf(f2 * rn); o[3] = f2bf(f3 * rn);
        *(s4v*)p = o;
    } else {
        const short* p = qkv + (long)n * PC3 + 2 * PC + t * 4;
        s4v v = *(const s4v*)p;
        float f0 = bf2f(v[0]), f1 = bf2f(v[1]), f2 = bf2f(v[2]), f3 = bf2f(v[3]);
        float ss = f0 * f0 + f1 * f1 + f2 * f2 + f3 * f3;
        ss += __shfl_xor(ss, 16, 64); ss += __shfl_xor(ss, 8, 64);
        ss += __shfl_xor(ss, 4, 64);  ss += __shfl_xor(ss, 2, 64);
        ss += __shfl_xor(ss, 1, 64);
        const float rn = rsqrtf(ss);
        s4v o;
        o[0] = f2bf(f0 * rn); o[1] = f2bf(f1 * rn);
        o[2] = f2bf(f2 * rn); o[3] = f2bf(f3 * rn);
        *(s4v*)(Vn + (long)n * PC + t * 4) = o;
        *(s4v*)(trans + (long)n * (2 * PC) + PC + t * 4) = v;
    }
}

// ---------------- reductions ----------------
__device__ __forceinline__ float wave_sum(float v) {
#pragma unroll
    for (int o = 32; o > 0; o >>= 1) v += __shfl_xor(v, o, 64);
    return v;
}
__device__ __forceinline__ float wave_max(float v) {
#pragma unroll
    for (int o = 32; o > 0; o >>= 1) v = fmaxf(v, __shfl_xor(v, o, 64));
    return v;
}
__device__ __forceinline__ float block_sum(float v, float* sm) {
    v = wave_sum(v);
    __syncthreads();
    if ((threadIdx.x & 63) == 0) sm[threadIdx.x >> 6] = v;
    __syncthreads();
    return sm[0] + sm[1] + sm[2] + sm[3];
}
__device__ __forceinline__ float block_max(float v, float* sm) {
    v = wave_max(v);
    __syncthreads();
    if ((threadIdx.x & 63) == 0) sm[threadIdx.x >> 6] = v;
    __syncthreads();
    return fmaxf(fmaxf(sm[0], sm[1]), fmaxf(sm[2], sm[3]));
}

// ---------------- sim_round2: head-sum attn8, softmax, mask, renorm ----------------
__global__ __launch_bounds__(256) void sim_round2_k(
    const short* __restrict__ attn8, const short* __restrict__ Sraw,
    short* __restrict__ Sout)
{
    __shared__ float sm[4];
    const long NN = (long)PN * PN;
    const long rowoff = (long)blockIdx.x * PN + threadIdx.x * 8;
    float v[8] = {0.f, 0.f, 0.f, 0.f, 0.f, 0.f, 0.f, 0.f};
#pragma unroll
    for (int h = 0; h < PH; ++h) {
        s8v a = *(const s8v*)&attn8[(long)h * NN + rowoff];
#pragma unroll
        for (int j = 0; j < 8; ++j) v[j] += bf2f(a[j]);
    }
    bool keep[8];
    {
        s8v raw = *(const s8v*)&Sraw[rowoff];
#pragma unroll
        for (int j = 0; j < 8; ++j) {
            v[j] *= 0.125f;
            keep[j] = bf2f(raw[j]) > 0.75f;
        }
    }
    float mx = -1e30f;
#pragma unroll
    for (int j = 0; j < 8; ++j) mx = fmaxf(mx, v[j]);
    mx = block_max(mx, sm);
    float sum = 0.f;
#pragma unroll
    for (int j = 0; j < 8; ++j) { v[j] = __expf(v[j] - mx); sum += v[j]; }
    sum = block_sum(sum, sm);
    const float inv = 1.0f / sum;
    float msum = 0.f;
#pragma unroll
    for (int j = 0; j < 8; ++j) { v[j] = keep[j] ? v[j] * inv : 0.f; msum += v[j]; }
    msum = block_sum(msum, sm);
    const float minv = 1.0f / msum;
    s8v o;
#pragma unroll
    for (int j = 0; j < 8; ++j) o[j] = f2bf(v[j] * minv);
    *(s8v*)&Sout[rowoff] = o;
}

// ---------------- host ----------------
extern "C" void kernel_launch(void* const* d_in, const int* in_sizes, int n_in,
                              void* d_out, int out_size, void* d_ws, size_t ws_size,
                              hipStream_t stream)
{
    (void)in_sizes; (void)n_in; (void)out_size; (void)ws_size;
    const float* x_cls = (const float*)d_in[0];
    const float* x_reg = (const float*)d_in[1];
    const float* cls_score = (const float*)d_in[2];
    const float* fg_score = (const float*)d_in[3];
    const float* Wqc = (const float*)d_in[4];
    const float* Wqr = (const float*)d_in[5];
    const float* W1 = (const float*)d_in[6];
    const float* b1 = (const float*)d_in[7];
    const float* W2 = (const float*)d_in[8];
    const float* b2 = (const float*)d_in[9];
    float* out = (float*)d_out;

    // ---- workspace (MiB offsets), peak ~156.2 MiB ----
    char* w = (char*)d_ws;
    short* qkv_cls_bf = (short*)(w + ((size_t)0   << 20)); // 12 MiB [N,3C]
    short* qkv_reg_bf = (short*)(w + ((size_t)12  << 20)); // 12 MiB (adjacent)
    short* attn8      = (short*)(w + ((size_t)24  << 20)); // 64 MiB [8][N,N] bf16
    short* sim_bf     = (short*)(w + ((size_t)88  << 20)); // 8 MiB
    short* sim_raw_bf = (short*)(w + ((size_t)104 << 20)); // 8 MiB
    short* Vn         = (short*)(w + ((size_t)112 << 20)); // 4 MiB
    short* vT         = (short*)(w + ((size_t)116 << 20)); // 4 MiB [C,N]
    short* bf_all     = (short*)(w + ((size_t)120 << 20)); // 36 MiB contiguous:
    short* x_cls_bf   = bf_all;                            //  @120, 4 MiB (x_reg @124 adj)
    short* Wqc_bf     = (short*)(w + ((size_t)128 << 20)); //  6 MiB (Wqr @134 adj)
    short* W1_bf      = (short*)(w + ((size_t)140 << 20)); //  8 MiB
    short* W2p_bf     = (short*)(w + ((size_t)148 << 20)); //  8 MiB [2048,2048] packed
    float* l_g        = (float*)(w + ((size_t)156 << 20)); // 128 KiB [2][8][N]
    // overlays (after underlying dead):
    short* trans      = (short*)(w + ((size_t)120 << 20)); // 8 MiB over x_* (post-QKV)
    short* feat       = (short*)(w + ((size_t)24  << 20)); // 8 MiB over attn8[0] (post r2)
    short* UVt        = (short*)(w + ((size_t)32  << 20)); // 8 MiB over attn8[1]

    const long NN = (long)PN * PN;

    // ---- fused fp32 -> bf16 (W2 packed) ----
    f2bf6_k<<<18432, 256, 0, stream>>>(x_cls, x_reg, Wqc, Wqr, W1, W2, bf_all);

    // ---- QKV projections, merged z=2 (v_reg computed wastefully) ----
    mfma_gemm_k<128, 64, true, false, false><<<dim3(48, 16, 2), 256, 0, stream>>>(
        x_cls_bf, PC, (long)PN * PC, Wqc_bf, PC, (long)PC3 * PC,
        qkv_cls_bf, PC3, (long)PN * PC3, PC, 1.0f, nullptr, nullptr, 0);

    // ---- norms; v transpose ----
    norms_k<<<dim3(PN, 5), 256, 0, stream>>>(qkv_cls_bf, Vn, trans);
    transpose_bf16_k<<<dim3(PC / 64, PN / 64), 256, 0, stream>>>(
        qkv_cls_bf + 2 * PC, PC3, vT, PN);

    // ---- sim_raw = (Vn @ Vn^T)/H ----
    mfma_gemm_k<128, 64, true, false, false><<<dim3(32, 16, 1), 256, 0, stream>>>(
        Vn, PC, 0, Vn, PC, 0, sim_raw_bf, PN, 0, PC, 0.125f, nullptr, nullptr, 0);

    // ---- attention: row sums + per-head tiles ----
    hipMemsetAsync(l_g, 0, (size_t)2 * PH * PN * sizeof(float), stream);
    attn_rowsum_k<<<dim3(16, PH, 8), 256, 0, stream>>>(
        qkv_cls_bf, cls_score, fg_score, l_g);
    attn_combine_k<<<dim3(16, 16, PH), 256, 0, stream>>>(
        qkv_cls_bf, cls_score, fg_score, l_g, attn8);

    // ---- x = attn @ v, z=8, BM=64 for 512 blocks ----
    mfma_gemm_k<64, 64, true, false, false><<<dim3(2, 32, PH), 256, 0, stream>>>(
        attn8, PN, NN, vT, PN, (long)PD * PN, trans, 2 * PC, PD, PN, 1.0f,
        nullptr, nullptr, 0);

    // ---- sim_round2 (head-sum folded in) ----
    sim_round2_k<<<PN, 256, 0, stream>>>(attn8, sim_raw_bf, sim_bf);

    // ---- feat = trans @ W1^T + b1 (bf16) ----
    mfma_gemm_k<128, 64, true, true, false><<<dim3(32, 16, 1), 256, 0, stream>>>(
        trans, 2 * PC, 0, W1_bf, 2 * PC, 0, feat, 2 * PC, 0, 2 * PC, 1.0f, b1,
        nullptr, 0);

    // ---- UVt = W2p @ feat^T : rows [0,1024)=U^T, [1024,2048)=V2^T ----
    mfma_gemm_k<128, 64, true, false, false><<<dim3(32, 16, 1), 256, 0, stream>>>(
        W2p_bf, 2 * PC, 0, feat, 2 * PC, 0, UVt, PN, 0, 2 * PC, 1.0f, nullptr,
        nullptr, 0);

    // ---- out = sim_bf @ (U^T)^T + V2 + b2 (transposed bf16 accumulate) ----
    mfma_gemm_k<128, 64, false, true, true><<<dim3(16, 16, 1), 256, 0, stream>>>(
        sim_bf, PN, 0, UVt, PN, 0, out, PC, 0, PN, 1.0f, b2,
        UVt + (long)PC * PN, PN);
}